// Round 11
// baseline (170.304 us; speedup 1.0000x reference)
//
#include <hip/hip_runtime.h>
#include <cstdint>
#include <cstddef>

// Problem constants (B, S, E, H, MAXLEN) = (2, 2048, 1024, 16, 2048)
constexpr int Sn = 2048;
constexpr int En = 1024;
constexpr int Bn = 2;
constexpr int Hn = 16;
constexpr int CHUNK = 32;          // 32-row chunks (2 per wave tile)
constexpr int NCH = Sn / CHUNK;    // 64 chunks per batch
constexpr int Mtot = Bn * Sn;      // 4096
constexpr int GCH = Mtot / CHUNK;  // 128 global chunks

typedef __bf16 bf16x8 __attribute__((ext_vector_type(8)));
typedef float  f32x4  __attribute__((ext_vector_type(4)));

__device__ __forceinline__ unsigned short f2bf(float f) {
    union { float f; uint32_t u; } v; v.f = f;
    const uint32_t u = v.u;
    return (unsigned short)((u + 0x7fffu + ((u >> 16) & 1u)) >> 16);  // RNE
}
__device__ __forceinline__ float bf2f(unsigned short s) {
    union { uint32_t u; float f; } v; v.u = (uint32_t)s << 16; return v.f;
}

// Light barrier: ds-write visibility only (lgkmcnt(0)), NO vmcnt drain.
// [R10: measured == __syncthreads (null), kept for zero-cost safety.]
__device__ __forceinline__ void barrier_light() {
    asm volatile("s_waitcnt lgkmcnt(0)" ::: "memory");
    __builtin_amdgcn_s_barrier();
}

// ---------------------------------------------------------------------------
// Fused fp32 -> bf16 cast of x (XN) and Wv (WN) in one launch.
// ---------------------------------------------------------------------------
constexpr int XN = Bn * Sn * En;   // 4194304
constexpr int WN = En * En;        // 1048576

__global__ __launch_bounds__(256)
void cast2(const float* __restrict__ x, const float* __restrict__ Wv,
           unsigned short* __restrict__ xb, unsigned short* __restrict__ Wvb)
{
    const int i = (blockIdx.x * 256 + threadIdx.x) * 4;
    const float* src; unsigned short* dst; int off;
    if (i < XN) { src = x;  dst = xb;  off = i; }
    else        { src = Wv; dst = Wvb; off = i - XN; }
    const float4 v = *(const float4*)(src + off);
    ushort4 o;
    o.x = f2bf(v.x); o.y = f2bf(v.y); o.z = f2bf(v.z); o.w = f2bf(v.w);
    *(ushort4*)(dst + off) = o;
}

// ---------------------------------------------------------------------------
// Shared GEMM macros (R10's verified dbuf structure).
// ---------------------------------------------------------------------------
#define LOAD6(k0, r0, r1, r2, r3, r4, r5)            \
    r0 = *(const uint4*)(gA0 + (k0));                \
    r1 = *(const uint4*)(gA0 + (k0) + 32);           \
    r2 = *(const uint4*)(gA1 + (k0));                \
    r3 = *(const uint4*)(gA1 + (k0) + 32);           \
    r4 = *(const uint4*)(gB0 + (k0));                \
    r5 = *(const uint4*)(gB0 + (k0) + 32);

#define STORE6B(B, r0, r1, r2, r3, r4, r5)                       \
    *(uint4*)&As[B][(rg0 * 2 + 0) * 512 + lane * 8] = r0;        \
    *(uint4*)&As[B][(rg0 * 2 + 1) * 512 + lane * 8] = r1;        \
    *(uint4*)&As[B][(rg1 * 2 + 0) * 512 + lane * 8] = r2;        \
    *(uint4*)&As[B][(rg1 * 2 + 1) * 512 + lane * 8] = r3;        \
    *(uint4*)&Bs[B][(wv  * 2 + 0) * 512 + lane * 8] = r4;        \
    *(uint4*)&Bs[B][(wv  * 2 + 1) * 512 + lane * 8] = r5;

#define COMPUTEB(B)                                                                            \
    {                                                                                          \
        bf16x8 af[4][2], bfr[2][2];                                                            \
        _Pragma("unroll")                                                                      \
        for (int i = 0; i < 4; ++i)                                                            \
            _Pragma("unroll")                                                                  \
            for (int kh = 0; kh < 2; ++kh)                                                     \
                af[i][kh] = *(const bf16x8*)&As[B][((wr * 4 + i) * 2 + kh) * 512 + lane * 8];   \
        _Pragma("unroll")                                                                      \
        for (int j = 0; j < 2; ++j)                                                            \
            _Pragma("unroll")                                                                  \
            for (int kh = 0; kh < 2; ++kh)                                                     \
                bfr[j][kh] = *(const bf16x8*)&Bs[B][((wc * 2 + j) * 2 + kh) * 512 + lane * 8]; \
        _Pragma("unroll")                                                                      \
        for (int kh = 0; kh < 2; ++kh)                                                         \
            _Pragma("unroll")                                                                  \
            for (int i = 0; i < 4; ++i)                                                        \
                _Pragma("unroll")                                                              \
                for (int j = 0; j < 2; ++j)                                                    \
                    acc[i][j] = __builtin_amdgcn_mfma_f32_16x16x32_bf16(af[i][kh], bfr[j][kh], \
                                                                        acc[i][j], 0, 0, 0);   \
    }

// ---------------------------------------------------------------------------
// gemm1_sk — R24: SPLIT-K=2 on gemm1. Per-step structure byte-identical to
// the verified R10 pipeline; 8 K-steps per block instead of 16; grid
// (16,32,2) = 1024 blocks = 4/CU; aggregate staged bytes IDENTICAL to the
// unsplit version (unlike R5's 64² retile, which changed per-step work).
// [Theory: per-CU time invariant to phase count & per-phase work (R3==R6);
// all overlap/drain/depth axes null -> remaining model = per-block serial
// K-depth x exposed phase latency with limited inter-block overlap. Split-K
// isolates serial depth.]
// Reduction folds into combine (mask & bias are linear): each half writes
// masked bf16 partials vm_k + fp32 csum_k; bias added by half ks==0 only.
// ---------------------------------------------------------------------------
__global__ __launch_bounds__(256)
void gemm1_sk(const unsigned short* __restrict__ A, const unsigned short* __restrict__ Bw,
              const float* __restrict__ bias, const int* __restrict__ mask,
              unsigned short* __restrict__ vm0, unsigned short* __restrict__ vm1,
              float* __restrict__ csum0, float* __restrict__ csum1)
{
    __shared__ __align__(16) unsigned short As[2][128 * 64];  // 2 x 16 KB
    __shared__ __align__(16) unsigned short Bs[2][64 * 64];   // 2 x 8 KB

    const int tid  = threadIdx.x;
    const int lane = tid & 63;
    const int wv   = tid >> 6;
    const int wr   = wv >> 1;
    const int wc   = wv & 1;
    const int id   = blockIdx.y * 16 + blockIdx.x;   // XCD swizzle as before
    const int xcd  = id & 7;
    const int slot = id >> 3;
    const int by   = xcd * 4 + (slot >> 4);
    const int bx   = slot & 15;
    const int bm   = by * 128;
    const int bn   = bx * 64;
    const int m16  = lane & 15;
    const int kq   = lane >> 4;
    const int ks   = blockIdx.z;        // K-half 0/1

    f32x4 acc[4][2] = {};

    const int rg0 = 2 * wv, rg1 = 2 * wv + 1;
    const size_t koff = (size_t)ks * 512;
    const unsigned short* gA0 = A  + (size_t)(bm + 16 * rg0 + m16) * En + koff + kq * 8;
    const unsigned short* gA1 = A  + (size_t)(bm + 16 * rg1 + m16) * En + koff + kq * 8;
    const unsigned short* gB0 = Bw + (size_t)(bn + 16 * wv  + m16) * En + koff + kq * 8;

    uint4 p0, p1, p2, p3, p4, p5;
    uint4 q0, q1, q2, q3, q4, q5;

    // 8 K-steps (tiles 0..7 of this half). Same dbuf pipeline as R10.
    LOAD6(0,  p0, p1, p2, p3, p4, p5);          // tile 0
    STORE6B(0, p0, p1, p2, p3, p4, p5);
    LOAD6(64, q0, q1, q2, q3, q4, q5);          // tile 1
    barrier_light();

#pragma unroll 1
    for (int it = 0; it < 3; ++it) {            // steps 0..5
        const int kb = it * 128;
        LOAD6(kb + 128, p0, p1, p2, p3, p4, p5);     // tile 2it+2
        COMPUTEB(0);
        STORE6B(1, q0, q1, q2, q3, q4, q5);
        barrier_light();
        LOAD6(kb + 192, q0, q1, q2, q3, q4, q5);     // tile 2it+3 (<=7)
        COMPUTEB(1);
        STORE6B(0, p0, p1, p2, p3, p4, p5);
        barrier_light();
    }
    // step 6: tile 6 in buf0; stage tile 7
    COMPUTEB(0);
    STORE6B(1, q0, q1, q2, q3, q4, q5);
    barrier_light();
    // step 7: tile 7
    COMPUTEB(1);

    // Epilogue: masked bf16 partial + fp32 partial colsum. bias in half 0.
    unsigned short* vmk = ks ? vm1 : vm0;
    float*          csk = ks ? csum1 : csum0;
    float colsum[2][2] = {{0.0f, 0.0f}, {0.0f, 0.0f}};
#pragma unroll
    for (int i = 0; i < 4; ++i) {
        const int r0_ = bm + wr * 64 + i * 16 + kq * 4;
#pragma unroll
        for (int j = 0; j < 2; ++j) {
            const int c0 = bn + wc * 32 + j * 16 + m16;
            const float bcol = (ks == 0) ? bias[c0] : 0.0f;
#pragma unroll
            for (int r = 0; r < 4; ++r) {
                const int row = r0_ + r;
                float val = acc[i][j][r] + bcol;
                val = (mask[row] == 0) ? 0.0f : val;   // mask is linear over K-halves
                colsum[i >> 1][j] += val;
                vmk[(size_t)row * En + c0] = f2bf(val);
            }
        }
    }
    {
        const int gc0 = 4 * by + 2 * wr;
#pragma unroll
        for (int g = 0; g < 2; ++g)
#pragma unroll
            for (int j = 0; j < 2; ++j) {
                float s = colsum[g][j];
                s += __shfl_xor(s, 16, 64);
                s += __shfl_xor(s, 32, 64);
                if (kq == 0)
                    csk[(size_t)(gc0 + g) * En + bn + wc * 32 + j * 16 + m16] = s;
            }
    }
}

// ---------------------------------------------------------------------------
// gemm2 — R10's verified gemm_pipe (16 steps, dbuf, light barriers).
// ---------------------------------------------------------------------------
template<bool APPLY_MASK, bool OUT_BF16, bool FUSE_CSUM>
__global__ __launch_bounds__(256)
void gemm_pipe(const unsigned short* __restrict__ A, const unsigned short* __restrict__ Bw,
               const float* __restrict__ bias, const int* __restrict__ mask,
               void* __restrict__ Cv, float* __restrict__ csum)
{
    __shared__ __align__(16) unsigned short As[2][128 * 64];
    __shared__ __align__(16) unsigned short Bs[2][64 * 64];

    const int tid  = threadIdx.x;
    const int lane = tid & 63;
    const int wv   = tid >> 6;
    const int wr   = wv >> 1;
    const int wc   = wv & 1;
    const int id   = blockIdx.y * 16 + blockIdx.x;
    const int xcd  = id & 7;
    const int slot = id >> 3;
    const int by   = xcd * 4 + (slot >> 4);
    const int bx   = slot & 15;
    const int bm   = by * 128;
    const int bn   = bx * 64;
    const int m16  = lane & 15;
    const int kq   = lane >> 4;

    f32x4 acc[4][2] = {};

    const int rg0 = 2 * wv, rg1 = 2 * wv + 1;
    const unsigned short* gA0 = A  + (size_t)(bm + 16 * rg0 + m16) * En + kq * 8;
    const unsigned short* gA1 = A  + (size_t)(bm + 16 * rg1 + m16) * En + kq * 8;
    const unsigned short* gB0 = Bw + (size_t)(bn + 16 * wv  + m16) * En + kq * 8;

    uint4 p0, p1, p2, p3, p4, p5;
    uint4 q0, q1, q2, q3, q4, q5;

    LOAD6(0,  p0, p1, p2, p3, p4, p5);
    STORE6B(0, p0, p1, p2, p3, p4, p5);
    LOAD6(64, q0, q1, q2, q3, q4, q5);
    barrier_light();

#pragma unroll 1
    for (int it = 0; it < 7; ++it) {
        const int kb = it * 128;
        LOAD6(kb + 128, p0, p1, p2, p3, p4, p5);
        COMPUTEB(0);
        STORE6B(1, q0, q1, q2, q3, q4, q5);
        barrier_light();
        LOAD6(kb + 192, q0, q1, q2, q3, q4, q5);
        COMPUTEB(1);
        STORE6B(0, p0, p1, p2, p3, p4, p5);
        barrier_light();
    }
    COMPUTEB(0);
    STORE6B(1, q0, q1, q2, q3, q4, q5);
    barrier_light();
    COMPUTEB(1);

    float colsum[2][2] = {{0.0f, 0.0f}, {0.0f, 0.0f}};
#pragma unroll
    for (int i = 0; i < 4; ++i) {
        const int r0_ = bm + wr * 64 + i * 16 + kq * 4;
#pragma unroll
        for (int j = 0; j < 2; ++j) {
            const int c0 = bn + wc * 32 + j * 16 + m16;
            const float bcol = bias[c0];
#pragma unroll
            for (int r = 0; r < 4; ++r) {
                const int row = r0_ + r;
                float val = acc[i][j][r] + bcol;
                if (APPLY_MASK) val = (mask[row] == 0) ? 0.0f : val;
                if (FUSE_CSUM) colsum[i >> 1][j] += val;
                if (OUT_BF16)
                    ((unsigned short*)Cv)[(size_t)row * En + c0] = f2bf(val);
                else
                    ((float*)Cv)[(size_t)row * En + c0] = val;
            }
        }
    }

    if (FUSE_CSUM) {
        const int gc0 = 4 * by + 2 * wr;
#pragma unroll
        for (int g = 0; g < 2; ++g)
#pragma unroll
            for (int j = 0; j < 2; ++j) {
                float s = colsum[g][j];
                s += __shfl_xor(s, 16, 64);
                s += __shfl_xor(s, 32, 64);
                if (kq == 0)
                    csum[(size_t)(gc0 + g) * En + bn + wc * 32 + j * 16 + m16] = s;
            }
    }
}

// ---------------------------------------------------------------------------
// combine (R24): sums the two split-K partials during staging (fp32 LDS
// tile), scans csum0+csum1, then the weighted combine -> opre (bf16).
//   out_pre[b,i,e] = (w2*Pref[i&~1] + (i odd)*w1*vm[i-1] + w0*(T-Pref[i]))/Z
// Mask & bias already applied in gemm1 halves (linear). Grid (4,64,2).
// LDS 32 KB fp32 tile -> still 2 blocks/CU.
// ---------------------------------------------------------------------------
__global__ __launch_bounds__(256)
void combine(const unsigned short* __restrict__ vm0, const unsigned short* __restrict__ vm1,
             const float* __restrict__ csum0, const float* __restrict__ csum1,
             const float* __restrict__ hier, const float* __restrict__ Wo,
             unsigned short* __restrict__ Wob, unsigned short* __restrict__ opre)
{
    __shared__ __align__(16) float tilef[CHUNK * 256];  // 32 KB

    const int tid = threadIdx.x;
    const int ec0 = blockIdx.x * 256;
    const int c   = blockIdx.y;     // chunk within batch, 0..63
    const int b   = blockIdx.z;

    // --- Stage 32x256 (vm0+vm1) tile -> fp32 LDS: 4 passes x 8 rows.
    {
        const int lane16 = tid & 31;          // 16B segment within a row
        const int rbase  = tid >> 5;          // 0..7
        const size_t g0 = ((size_t)b * Sn + c * CHUNK) * En + ec0 + lane16 * 8;
#pragma unroll
        for (int r4 = 0; r4 < 4; ++r4) {
            const int row = r4 * 8 + rbase;
            const uint4 va = *(const uint4*)(vm0 + g0 + (size_t)row * En);
            const uint4 vb = *(const uint4*)(vm1 + g0 + (size_t)row * En);
            const unsigned short* pa = (const unsigned short*)&va;
            const unsigned short* pb = (const unsigned short*)&vb;
            float* d = &tilef[row * 256 + lane16 * 8];
#pragma unroll
            for (int k = 0; k < 8; ++k)
                d[k] = bf2f(pa[k]) + bf2f(pb[k]);
        }
    }

    // --- Wo cast slice: 512 blocks x 256 threads x 8 elems = 1M elements.
    {
        const int fid = (blockIdx.z * 64 + blockIdx.y) * 4 + blockIdx.x;  // 0..511
        const int base = fid * 2048 + tid * 4;
#pragma unroll
        for (int half = 0; half < 2; ++half) {
            const int off = base + half * 1024;
            const float4 v = *(const float4*)(Wo + off);
            ushort4 o;
            o.x = f2bf(v.x); o.y = f2bf(v.y); o.z = f2bf(v.z); o.w = f2bf(v.w);
            *(ushort4*)(Wob + off) = o;
        }
    }

    const int e = ec0 + tid;
    const int h = e >> 6;   // dh = 64
    const float w0 = hier[((size_t)b * Hn + h) * 3 + 0];
    const float w1 = hier[((size_t)b * Hn + h) * 3 + 1] * 0.5f;
    const float w2 = hier[((size_t)b * Hn + h) * 3 + 2] * 0.25f;

    // --- Exclusive scan over csum0+csum1 (64 chunk sums per column).
    float run = 0.0f, T = 0.0f;
    {
        const float* cp0 = csum0 + (size_t)b * NCH * En + e;
        const float* cp1 = csum1 + (size_t)b * NCH * En + e;
#pragma unroll 16
        for (int c2 = 0; c2 < NCH; ++c2) {
            const float v = cp0[(size_t)c2 * En] + cp1[(size_t)c2 * En];
            T += v;
            run += (c2 < c) ? v : 0.0f;
        }
    }

    __syncthreads();   // vm tile visible

    float prev = 0.0f;
    const size_t base = ((size_t)b * Sn + c * CHUNK) * En + e;

#pragma unroll
    for (int t = 0; t < CHUNK; ++t) {
        const int i = c * CHUNK + t;
        const float cur = tilef[t * 256 + tid];
        float num, Z;
        if (i & 1) {
            num = w2 * (run - prev) + w1 * prev + w0 * (T - run);
            Z = (float)(i - 1) * w2 + w1 + (float)(Sn - i) * w0 + 1e-8f;
        } else {
            num = w2 * run + w0 * (T - run);
            Z = (float)i * w2 + (float)(Sn - i) * w0 + 1e-8f;
        }
        opre[base + (size_t)t * En] = f2bf(num / Z);
        run += cur;
        prev = cur;
    }
}

// ---------------------------------------------------------------------------
extern "C" void kernel_launch(void* const* d_in, const int* in_sizes, int n_in,
                              void* d_out, int out_size, void* d_ws, size_t ws_size,
                              hipStream_t stream)
{
    // 0:x 1:attention_mask 2:level_indices 3:Wq 4:bq 5:Wk 6:bk 7:Wv 8:bv 9:hier 10:Wo 11:bo
    const float* x    = (const float*)d_in[0];
    const int*   mask = (const int*)d_in[1];
    const float* Wv   = (const float*)d_in[7];
    const float* bv   = (const float*)d_in[8];
    const float* hier = (const float*)d_in[9];
    const float* Wo   = (const float*)d_in[10];
    const float* bo   = (const float*)d_in[11];
    float* out = (float*)d_out;

    char* ws = (char*)d_ws;
    unsigned short* xb    = (unsigned short*)ws;  ws += (size_t)Mtot * En * 2;   // 8 MB
    unsigned short* Wvb   = (unsigned short*)ws;  ws += (size_t)En * En * 2;     // 2 MB
    unsigned short* Wob   = (unsigned short*)ws;  ws += (size_t)En * En * 2;     // 2 MB
    unsigned short* vmb0  = (unsigned short*)ws;  ws += (size_t)Mtot * En * 2;   // 8 MB
    unsigned short* vmb1  = (unsigned short*)ws;  ws += (size_t)Mtot * En * 2;   // 8 MB
    float*          csum0 = (float*)ws;           ws += (size_t)GCH * En * 4;    // 512 KB
    float*          csum1 = (float*)ws;           ws += (size_t)GCH * En * 4;    // 512 KB
    unsigned short* opreb = (unsigned short*)ws;  ws += (size_t)Mtot * En * 2;   // 8 MB

    dim3 threads(256);

    // Casts to bf16: x + Wv only (Wo is cast inside combine, pre-gemm2)
    cast2<<<dim3((XN + WN) / 1024), threads, 0, stream>>>(x, Wv, xb, Wvb);

    // 1) split-K=2: vm_k = mask ? partial_k(x @ Wv.T) (+bv in k=0) : 0 (bf16)
    //    + per-half fp32 chunk col sums. 1024 blocks = 4/CU.
    gemm1_sk<<<dim3(16, 32, 2), threads, 0, stream>>>(xb, Wvb, bv, mask,
                                                      vmb0, vmb1, csum0, csum1);
    // 2) Wo cast + (vm0+vm1) staging + scan(csum0+csum1) + combine -> opre
    combine<<<dim3(En / 256, NCH, Bn), threads, 0, stream>>>(vmb0, vmb1, csum0, csum1,
                                                             hier, Wo, Wob, opreb);
    // 3) out = opre @ Wo.T + bo (fp32 out), unsplit (no cheap reduction sink)
    gemm_pipe<false, false, false><<<dim3(16, 32), threads, 0, stream>>>(opreb, Wob, bo,
                                                                         nullptr, out, nullptr);
}

// Round 12
// 163.172 us; speedup vs baseline: 1.0437x; 1.0437x over previous
//
#include <hip/hip_runtime.h>
#include <cstdint>
#include <cstddef>

// Problem constants (B, S, E, H, MAXLEN) = (2, 2048, 1024, 16, 2048)
constexpr int Sn = 2048;
constexpr int En = 1024;
constexpr int Bn = 2;
constexpr int Hn = 16;
constexpr int CHUNK = 32;          // 32-row chunks (2 per wave tile)
constexpr int NCH = Sn / CHUNK;    // 64 chunks per batch
constexpr int Mtot = Bn * Sn;      // 4096
constexpr int GCH = Mtot / CHUNK;  // 128 global chunks

typedef __bf16 bf16x8 __attribute__((ext_vector_type(8)));
typedef float  f32x4  __attribute__((ext_vector_type(4)));

__device__ __forceinline__ unsigned short f2bf(float f) {
    union { float f; uint32_t u; } v; v.f = f;
    const uint32_t u = v.u;
    return (unsigned short)((u + 0x7fffu + ((u >> 16) & 1u)) >> 16);  // RNE
}
__device__ __forceinline__ float bf2f(unsigned short s) {
    union { uint32_t u; float f; } v; v.u = (uint32_t)s << 16; return v.f;
}

// ---------------------------------------------------------------------------
// Fused fp32 -> bf16 cast of x (XN) and Wv (WN) in one launch.
// [R15: in-GEMM fp32 staging +16 µs. R7: coop fusion +200 µs. R11: split-K
// +7 µs. This 4-dispatch decomposition is the measured optimum.]
// ---------------------------------------------------------------------------
constexpr int XN = Bn * Sn * En;   // 4194304
constexpr int WN = En * En;        // 1048576

__global__ __launch_bounds__(256)
void cast2(const float* __restrict__ x, const float* __restrict__ Wv,
           unsigned short* __restrict__ xb, unsigned short* __restrict__ Wvb)
{
    const int i = (blockIdx.x * 256 + threadIdx.x) * 4;
    const float* src; unsigned short* dst; int off;
    if (i < XN) { src = x;  dst = xb;  off = i; }
    else        { src = Wv; dst = Wvb; off = i - XN; }
    const float4 v = *(const float4*)(src + off);
    ushort4 o;
    o.x = f2bf(v.x); o.y = f2bf(v.y); o.z = f2bf(v.z); o.w = f2bf(v.w);
    *(ushort4*)(dst + off) = o;
}

// ---------------------------------------------------------------------------
// bf16 MFMA GEMM (NT) — R8 configuration (session best: 163.06 µs total).
// C[m,n] = sum_k A[m,k]*W[n,k] + bias[n].
// Tile 128(M) x 64(N), BK=64, 256 threads = 4 waves in 2x2, wave tile 64x32.
// LDS double-buffer: step t reads buf[t&1], stores tile t+1 AFTER compute.
// [PLATEAU NOTE — 15 structural variants across 2 sessions all land at
// 34-40 µs/GEMM at this shape (M=4096,N=1024,K=1024 ~ 253 TF, the m102
// shape-curve value for this family): prefetch depth, staged dtype, tile
// 64²/128x64/128², glds vs reg-stage, flatmm, BK 32/64/128, barrier count,
// light-vs-heavy barriers, no-LDS direct, split-K, coop fusion, 4-blk
// occupancy. Counters at plateau: MfmaUtil ~6%, VALUBusy ~7%, HBM ~8%,
// 0 bank conflicts — latency-bound small-shape regime; per-CU time is
// invariant to phase count and per-phase work (R3==R6). Do not re-enter
// this family without a fundamentally different schedule (8-phase 256²
// needs >=256 blocks at that tile; this shape yields 64).]
// Chunk = 16 rows x 32 k in fragment order, lane l -> slot l*16 B
// (conflict-free b128). XCD swizzle: xcd = id&7 owns 4 contiguous
// row-blocks (A 1 MB + B 2 MB < 4 MB per-XCD L2).
// FUSE_CSUM: wave wr's 64 rows = global chunks {4*by+2*wr, +1}; butterfly
// over kq, unique writer kq==0.
// ---------------------------------------------------------------------------
#define LOAD6(k0, r0, r1, r2, r3, r4, r5)            \
    r0 = *(const uint4*)(gA0 + (k0));                \
    r1 = *(const uint4*)(gA0 + (k0) + 32);           \
    r2 = *(const uint4*)(gA1 + (k0));                \
    r3 = *(const uint4*)(gA1 + (k0) + 32);           \
    r4 = *(const uint4*)(gB0 + (k0));                \
    r5 = *(const uint4*)(gB0 + (k0) + 32);

#define STORE6B(B, r0, r1, r2, r3, r4, r5)                       \
    *(uint4*)&As[B][(rg0 * 2 + 0) * 512 + lane * 8] = r0;        \
    *(uint4*)&As[B][(rg0 * 2 + 1) * 512 + lane * 8] = r1;        \
    *(uint4*)&As[B][(rg1 * 2 + 0) * 512 + lane * 8] = r2;        \
    *(uint4*)&As[B][(rg1 * 2 + 1) * 512 + lane * 8] = r3;        \
    *(uint4*)&Bs[B][(wv  * 2 + 0) * 512 + lane * 8] = r4;        \
    *(uint4*)&Bs[B][(wv  * 2 + 1) * 512 + lane * 8] = r5;

#define COMPUTEB(B)                                                                            \
    {                                                                                          \
        bf16x8 af[4][2], bfr[2][2];                                                            \
        _Pragma("unroll")                                                                      \
        for (int i = 0; i < 4; ++i)                                                            \
            _Pragma("unroll")                                                                  \
            for (int kh = 0; kh < 2; ++kh)                                                     \
                af[i][kh] = *(const bf16x8*)&As[B][((wr * 4 + i) * 2 + kh) * 512 + lane * 8];   \
        _Pragma("unroll")                                                                      \
        for (int j = 0; j < 2; ++j)                                                            \
            _Pragma("unroll")                                                                  \
            for (int kh = 0; kh < 2; ++kh)                                                     \
                bfr[j][kh] = *(const bf16x8*)&Bs[B][((wc * 2 + j) * 2 + kh) * 512 + lane * 8]; \
        _Pragma("unroll")                                                                      \
        for (int kh = 0; kh < 2; ++kh)                                                         \
            _Pragma("unroll")                                                                  \
            for (int i = 0; i < 4; ++i)                                                        \
                _Pragma("unroll")                                                              \
                for (int j = 0; j < 2; ++j)                                                    \
                    acc[i][j] = __builtin_amdgcn_mfma_f32_16x16x32_bf16(af[i][kh], bfr[j][kh], \
                                                                        acc[i][j], 0, 0, 0);   \
    }

template<bool APPLY_MASK, bool OUT_BF16, bool FUSE_CSUM>
__global__ __launch_bounds__(256)
void gemm_pipe(const unsigned short* __restrict__ A, const unsigned short* __restrict__ Bw,
               const float* __restrict__ bias, const int* __restrict__ mask,
               void* __restrict__ Cv, float* __restrict__ csum)
{
    __shared__ __align__(16) unsigned short As[2][128 * 64];  // 2 x 16 KB
    __shared__ __align__(16) unsigned short Bs[2][64 * 64];   // 2 x 8 KB

    const int tid  = threadIdx.x;
    const int lane = tid & 63;
    const int wv   = tid >> 6;      // wave 0..3
    const int wr   = wv >> 1;       // wave row (0..1) -> M
    const int wc   = wv & 1;        // wave col (0..1) -> N
    // XCD-aware swizzle (grid (16, 32)).
    const int id   = blockIdx.y * 16 + blockIdx.x;
    const int xcd  = id & 7;
    const int slot = id >> 3;
    const int by   = xcd * 4 + (slot >> 4);
    const int bx   = slot & 15;
    const int bm   = by * 128;
    const int bn   = bx * 64;
    const int m16  = lane & 15;
    const int kq   = lane >> 4;     // k-quarter (staging) / row-quad (C/D)

    f32x4 acc[4][2] = {};

    const int rg0 = 2 * wv, rg1 = 2 * wv + 1;
    const unsigned short* gA0 = A  + (size_t)(bm + 16 * rg0 + m16) * En + kq * 8;
    const unsigned short* gA1 = A  + (size_t)(bm + 16 * rg1 + m16) * En + kq * 8;
    const unsigned short* gB0 = Bw + (size_t)(bn + 16 * wv  + m16) * En + kq * 8;

    // 12 individually named staging registers (arrays spill — R6 lesson).
    uint4 p0, p1, p2, p3, p4, p5;
    uint4 q0, q1, q2, q3, q4, q5;

    // Pipeline: step t reads buf[t&1]; stores for tile t+1 happen at step t
    // AFTER compute. K=1024, BK=64 -> 16 K-steps.
    LOAD6(0,  p0, p1, p2, p3, p4, p5);          // tile 0
    STORE6B(0, p0, p1, p2, p3, p4, p5);         // waits vmcnt(0) once
    LOAD6(64, q0, q1, q2, q3, q4, q5);          // tile 1
    __syncthreads();                            // buf0 ready

#pragma unroll 1
    for (int it = 0; it < 7; ++it) {            // steps 0..13
        const int kb = it * 128;
        // even step 2it: read buf0
        LOAD6(kb + 128, p0, p1, p2, p3, p4, p5);     // tile 2it+2
        COMPUTEB(0);
        STORE6B(1, q0, q1, q2, q3, q4, q5);          // tile 2it+1
        __syncthreads();
        // odd step 2it+1: read buf1
        LOAD6(kb + 192, q0, q1, q2, q3, q4, q5);     // tile 2it+3
        COMPUTEB(1);
        STORE6B(0, p0, p1, p2, p3, p4, p5);          // tile 2it+2
        __syncthreads();
    }
    // step 14: read buf0 (tile 14); stage tile 15
    COMPUTEB(0);
    STORE6B(1, q0, q1, q2, q3, q4, q5);
    __syncthreads();
    // step 15: read buf1 (tile 15)
    COMPUTEB(1);

    // Epilogue. C/D layout: col = lane&15, row = (lane>>4)*4 + reg.
    // colsum[g][j]: g = 32-row half of the wave tile, j = 16-col group.
    float colsum[2][2] = {{0.0f, 0.0f}, {0.0f, 0.0f}};
#pragma unroll
    for (int i = 0; i < 4; ++i) {
        const int r0_ = bm + wr * 64 + i * 16 + kq * 4;
#pragma unroll
        for (int j = 0; j < 2; ++j) {
            const int c0 = bn + wc * 32 + j * 16 + m16;
            const float bcol = bias[c0];
#pragma unroll
            for (int r = 0; r < 4; ++r) {
                const int row = r0_ + r;
                float val = acc[i][j][r] + bcol;
                if (APPLY_MASK) val = (mask[row] == 0) ? 0.0f : val;
                if (FUSE_CSUM) colsum[i >> 1][j] += val;
                if (OUT_BF16)
                    ((unsigned short*)Cv)[(size_t)row * En + c0] = f2bf(val);
                else
                    ((float*)Cv)[(size_t)row * En + c0] = val;
            }
        }
    }

    if (FUSE_CSUM) {
        // Wave wr's 64 rows = global chunks {4*by + 2*wr, +1} (CHUNK=32).
        const int gc0 = 4 * by + 2 * wr;
#pragma unroll
        for (int g = 0; g < 2; ++g)
#pragma unroll
            for (int j = 0; j < 2; ++j) {
                float s = colsum[g][j];
                s += __shfl_xor(s, 16, 64);
                s += __shfl_xor(s, 32, 64);
                if (kq == 0)
                    csum[(size_t)(gc0 + g) * En + bn + wc * 32 + j * 16 + m16] = s;
            }
    }
}

// ---------------------------------------------------------------------------
// combine (R16 structure): Wo cast slice + LDS-staged vm tile + pipelined
// csum scan + weighted combine -> opre (bf16).
//   out_pre[b,i,e] = (w2*Pref[i&~1] + (i odd)*w1*vm[i-1] + w0*(T-Pref[i]))/Z
//   Z = (i&~1)*w2 + (i odd)*w1 + (S-i)*w0 + 1e-8
// Grid (4, 64, 2) = 512 blocks = 2/CU. Chunk starts even, so odd-i prev is
// always in-chunk. gemm2 (reads Wob) launches after us.
// ---------------------------------------------------------------------------
__global__ __launch_bounds__(256)
void combine(const unsigned short* __restrict__ vm, const float* __restrict__ csum,
             const float* __restrict__ hier, const float* __restrict__ Wo,
             unsigned short* __restrict__ Wob, unsigned short* __restrict__ opre)
{
    __shared__ __align__(16) unsigned short tile[CHUNK * 256];  // 16 KB

    const int tid = threadIdx.x;
    const int ec0 = blockIdx.x * 256;
    const int c   = blockIdx.y;     // chunk within batch, 0..63
    const int b   = blockIdx.z;

    // --- Stage 32x256 vm tile -> LDS: 4 passes x (8 rows x 32 lanes x 16 B).
    {
        const int lane16 = tid & 31;          // 16B segment within a row
        const int rbase  = tid >> 5;          // 0..7
        const size_t g0 = ((size_t)b * Sn + c * CHUNK) * En + ec0 + lane16 * 8;
#pragma unroll
        for (int r4 = 0; r4 < 4; ++r4) {
            const int row = r4 * 8 + rbase;
            *(uint4*)&tile[row * 256 + lane16 * 8] =
                *(const uint4*)(vm + g0 + (size_t)row * En);
        }
    }

    // --- Wo cast slice: 512 blocks x 256 threads x 8 elems = 1M elements.
    {
        const int fid = (blockIdx.z * 64 + blockIdx.y) * 4 + blockIdx.x;  // 0..511
        const int base = fid * 2048 + tid * 4;
#pragma unroll
        for (int half = 0; half < 2; ++half) {
            const int off = base + half * 1024;
            const float4 v = *(const float4*)(Wo + off);
            ushort4 o;
            o.x = f2bf(v.x); o.y = f2bf(v.y); o.z = f2bf(v.z); o.w = f2bf(v.w);
            *(ushort4*)(Wob + off) = o;
        }
    }

    const int e = ec0 + tid;
    const int h = e >> 6;   // dh = 64
    const float w0 = hier[((size_t)b * Hn + h) * 3 + 0];
    const float w1 = hier[((size_t)b * Hn + h) * 3 + 1] * 0.5f;
    const float w2 = hier[((size_t)b * Hn + h) * 3 + 2] * 0.25f;

    // --- Exclusive scan over this batch's 64 chunk sums (coalesced, x16
    //     unrolled so loads cluster; c is block-uniform -> branchless add).
    float run = 0.0f, T = 0.0f;
    {
        const float* cp = csum + (size_t)b * NCH * En + e;
#pragma unroll 16
        for (int c2 = 0; c2 < NCH; ++c2) {
            const float v = cp[(size_t)c2 * En];
            T += v;
            run += (c2 < c) ? v : 0.0f;
        }
    }

    __syncthreads();   // vm tile visible

    float prev = 0.0f;
    const size_t base = ((size_t)b * Sn + c * CHUNK) * En + e;

#pragma unroll
    for (int t = 0; t < CHUNK; ++t) {
        const int i = c * CHUNK + t;
        const float cur = bf2f(tile[t * 256 + tid]);
        float num, Z;
        if (i & 1) {
            num = w2 * (run - prev) + w1 * prev + w0 * (T - run);
            Z = (float)(i - 1) * w2 + w1 + (float)(Sn - i) * w0 + 1e-8f;
        } else {
            num = w2 * run + w0 * (T - run);
            Z = (float)i * w2 + (float)(Sn - i) * w0 + 1e-8f;
        }
        opre[base + (size_t)t * En] = f2bf(num / Z);
        run += cur;
        prev = cur;
    }
}

// ---------------------------------------------------------------------------
extern "C" void kernel_launch(void* const* d_in, const int* in_sizes, int n_in,
                              void* d_out, int out_size, void* d_ws, size_t ws_size,
                              hipStream_t stream)
{
    // 0:x 1:attention_mask 2:level_indices 3:Wq 4:bq 5:Wk 6:bk 7:Wv 8:bv 9:hier 10:Wo 11:bo
    const float* x    = (const float*)d_in[0];
    const int*   mask = (const int*)d_in[1];
    const float* Wv   = (const float*)d_in[7];
    const float* bv   = (const float*)d_in[8];
    const float* hier = (const float*)d_in[9];
    const float* Wo   = (const float*)d_in[10];
    const float* bo   = (const float*)d_in[11];
    float* out = (float*)d_out;

    char* ws = (char*)d_ws;
    unsigned short* xb    = (unsigned short*)ws;  ws += (size_t)Mtot * En * 2;   // 8 MB
    unsigned short* Wvb   = (unsigned short*)ws;  ws += (size_t)En * En * 2;     // 2 MB
    unsigned short* Wob   = (unsigned short*)ws;  ws += (size_t)En * En * 2;     // 2 MB
    unsigned short* vmb   = (unsigned short*)ws;  ws += (size_t)Mtot * En * 2;   // 8 MB
    float*          csum  = (float*)ws;           ws += (size_t)GCH * En * 4;    // 512 KB
    unsigned short* opreb = (unsigned short*)ws;  ws += (size_t)Mtot * En * 2;   // 8 MB

    dim3 threads(256);

    // Casts to bf16: x + Wv only (Wo is cast inside combine, pre-gemm2)
    cast2<<<dim3((XN + WN) / 1024), threads, 0, stream>>>(x, Wv, xb, Wvb);

    dim3 gemm_grid(16, 32);   // 512 blocks = 2/CU (XCD-swizzled in-kernel)

    // 1) vm = mask ? (x @ Wv.T + bv) : 0 (bf16) + fused 32-row chunk col sums
    gemm_pipe<true, true, true><<<gemm_grid, threads, 0, stream>>>(xb, Wvb, bv, mask, vmb, csum);
    // 2) Wo cast + LDS-staged weighted combine (inline csum scan) -> opre (bf16)
    combine<<<dim3(En / 256, NCH, Bn), threads, 0, stream>>>(vmb, csum, hier, Wo, Wob, opreb);
    // 3) out = opre @ Wo.T + bo (fp32 out)
    gemm_pipe<false, false, false><<<gemm_grid, threads, 0, stream>>>(opreb, Wob, bo, nullptr, out, nullptr);
}